// Round 1
// 161.715 us; speedup vs baseline: 1.1549x; 1.1549x over previous
//
#include <hip/hip_runtime.h>

#define NGRAPH 1000
#define P      100
#define EPG    1200
#define INF    16
#define HID    64
#define NOUT   5

// r19: dense-MFMA propagation (replaces the per-edge LDS gather entirely).
//  - A_int[g] = 100x128 bf16 adjacency COUNT matrix (small ints, bf16-exact),
//    built per-graph by abuild() into global d_ws (L2-resident, 25.6 MB).
//  - Each Cheb hop = MFMA: T = -d^2 * (A_int @ Y), with Y split hi/lo at the
//    B-fragment (A_int exact => only 2 MFMAs/k-step for ~fp32 precision).
//  - 16-col chunks: prop1 -> T1 slot, prop2 -> T2 slot, then 2 K-steps of the
//    split-bf16 W matmul with chunk K-layout [Y16|T1_16|T2_16|zero16]
//    (wprep tables now carry 16 zero rows: RK = 3F+16).
//  - LDS = single A[100][100] f32 (40,000 B) -> 4 blocks/CU preserved.
//    Row layout: Y cols 0..63 | dinv 64 | deg 65 | T1 68..83 | T2 84..99.
//    ASTR=100 -> 8 bank-stagger positions (was 4 at ASTR=88).
//  - M-tiling: tiles 0..5 rows t*16, tile 6 remapped to rows 84..99 with a
//    row>=96 store guard (keeps storage at exactly 100 rows).
//  - d_ws: wt tables 122,880 B + A_int 25,600,000 B  (needs ws >= 25.8 MB).
// HARD RULES kept: acc arrays compile-time unrolled only; verified MFMA
// lane mappings (A: row=l&15,k=8*(l>>4)+j; B: col=l&15; D: col=l&15,
// row=4*(l>>4)+reg) reused verbatim from the 186us kernel.

#define ASTR   100
#define DINVC  64
#define DEGC   65
#define T1OFF  68
#define T2OFF  84

#define AINT_K   128
#define AINT_SZ  (P * AINT_K)     // 12800 shorts per graph

// wt table offsets (shorts). L1: RK=64 (48 real + 16 zero). L2/L3: RK=208.
#define RK1    64
#define RK2    208
#define L1HI   0
#define L1LO   4096
#define L2HI   8192
#define L2LO   21504
#define L3HI   34816
#define L3LO   48128
#define WT_SHORTS 61440

typedef short short8 __attribute__((ext_vector_type(8)));
typedef float f32x4  __attribute__((ext_vector_type(4)));

__device__ __forceinline__ void bsplit(float x, short& h, short& l) {
    unsigned u = __float_as_uint(x);
    h = (short)(u >> 16);
    float hf = __uint_as_float(u & 0xffff0000u);
    l = (short)(__float_as_uint(x - hf) >> 16);
}

// ---- W split/transpose pre-kernel ----
__global__ __launch_bounds__(256) void wprep(
    const float* __restrict__ W1, const float* __restrict__ W2,
    const float* __restrict__ W3, short* __restrict__ wt)
{
    const int i0 = blockIdx.x * blockDim.x + threadIdx.x;
    const int stride = gridDim.x * blockDim.x;
    for (int e = i0; e < HID * RK1; e += stride) {
        int c = e / RK1, r = e % RK1;
        float v = (r < 3 * INF) ? W1[r * HID + c] : 0.f;
        short h, l; bsplit(v, h, l);
        wt[L1HI + e] = h;
        wt[L1LO + e] = l;
    }
    for (int e = i0; e < HID * RK2; e += stride) {
        int c = e / RK2, r = e % RK2;
        float v2 = (r < 3 * HID) ? W2[r * HID + c] : 0.f;
        float v3 = (r < 3 * HID) ? W3[r * HID + c] : 0.f;
        short h, l;
        bsplit(v2, h, l); wt[L2HI + e] = h; wt[L2LO + e] = l;
        bsplit(v3, h, l); wt[L3HI + e] = h; wt[L3LO + e] = l;
    }
}

// ---- per-graph dense adjacency build: counts (u16 halves) -> bf16 ----
__global__ __launch_bounds__(256) void abuild(
    const int* __restrict__ src, const int* __restrict__ dst,
    short* __restrict__ aint)
{
    __shared__ unsigned int cnt[AINT_SZ / 2];     // 25,600 B
    const int g = blockIdx.x, tid = threadIdx.x, base = g * P;
    for (int i = tid; i < AINT_SZ / 2; i += 256) cnt[i] = 0u;
    __syncthreads();
    const int* srcg = src + g * EPG;
    const int* dstg = dst + g * EPG;
    for (int e = tid; e < EPG; e += 256) {
        int s = srcg[e] - base;
        int d = dstg[e] - base;
        int idx = d * AINT_K + s;
        atomicAdd(&cnt[idx >> 1], 1u << ((idx & 1) * 16));
    }
    __syncthreads();
    unsigned int* outw = (unsigned int*)(aint + (size_t)g * AINT_SZ);
    for (int i = tid; i < AINT_SZ / 2; i += 256) {
        unsigned int u = cnt[i];
        unsigned int b0 = __float_as_uint((float)(u & 0xffffu)) >> 16;
        unsigned int b1 = __float_as_uint((float)(u >> 16)) >> 16;
        outw[i] = b0 | (b1 << 16);
    }
}

// ---- one dense propagation: dst slot = -d^2*(Aint@src)  (SECOND: -2d^2*.. - Y)
template <int SECOND>
__device__ __forceinline__ void dense_prop(
    float* __restrict__ A, const short* __restrict__ aintg,
    int arow0, int arow1, bool has2,
    int srcoff, int dstoff, int ycol,
    int rb0, int rb1, f32x4 dv0, f32x4 dv1, int lane)
{
    const int n16 = lane & 15;
    const int q   = lane >> 4;
    const int kq  = q * 8;
    f32x4 p0, p1;
    p0[0]=0.f; p0[1]=0.f; p0[2]=0.f; p0[3]=0.f;
    p1[0]=0.f; p1[1]=0.f; p1[2]=0.f; p1[3]=0.f;
#pragma unroll
    for (int k = 0; k < 4; k++) {
        const short8 a0 = *(const short8*)&aintg[arow0 * AINT_K + k * 32 + kq];
        const short8 a1 = *(const short8*)&aintg[arow1 * AINT_K + k * 32 + kq];
        short8 bhi, blo; short h, l;
#pragma unroll
        for (int j = 0; j < 8; j++) {
            int row = k * 32 + kq + j;
            if (k == 3) row = (row < P) ? row : 0;   // Aint cols >=100 are 0
            float x = A[row * ASTR + srcoff + n16];
            bsplit(x, h, l); bhi[j] = h; blo[j] = l;
        }
        p0 = __builtin_amdgcn_mfma_f32_16x16x32_bf16(a0, bhi, p0, 0, 0, 0);
        p0 = __builtin_amdgcn_mfma_f32_16x16x32_bf16(a0, blo, p0, 0, 0, 0);
        if (has2) {
            p1 = __builtin_amdgcn_mfma_f32_16x16x32_bf16(a1, bhi, p1, 0, 0, 0);
            p1 = __builtin_amdgcn_mfma_f32_16x16x32_bf16(a1, blo, p1, 0, 0, 0);
        }
    }
#pragma unroll
    for (int r = 0; r < 4; r++) {
        const int row = rb0 + q * 4 + r;
        const float d2 = dv0[r] * dv0[r];
        float o;
        if (SECOND) o = -2.f * d2 * p0[r] - A[row * ASTR + ycol];
        else        o = -d2 * p0[r];
        A[row * ASTR + dstoff + n16] = o;
    }
    if (has2) {
#pragma unroll
        for (int r = 0; r < 4; r++) {
            const int row = rb1 + q * 4 + r;
            if (rb1 != 84 || row >= 96) {            // tile-6 overlap guard
                const float d2 = dv1[r] * dv1[r];
                float o;
                if (SECOND) o = -2.f * d2 * p1[r] - A[row * ASTR + ycol];
                else        o = -d2 * p1[r];
                A[row * ASTR + dstoff + n16] = o;
            }
        }
    }
}

// ---- one ChebConv layer ----
template <int F, int FINAL>
__device__ __forceinline__ void cheb_layer(
    float* __restrict__ A, const short* __restrict__ aintg,
    const short* __restrict__ whi, const short* __restrict__ wlo,
    const float* __restrict__ bias,
    int tid, int rb0, int rb1, bool has2, f32x4 dv0, f32x4 dv1)
{
    const int RK   = 3 * F + 16;
    const int lane = tid & 63;
    const int wv   = tid >> 6;
    const int n16  = lane & 15;
    const int q    = lane >> 4;
    const int ncol = (wv << 4) + n16;

    const int arow0 = rb0 + n16;
    const int arow1 = (has2 ? rb1 : rb0) + n16;

    f32x4 acc[7];
#pragma unroll
    for (int t = 0; t < 7; t++) { acc[t][0]=0.f; acc[t][1]=0.f; acc[t][2]=0.f; acc[t][3]=0.f; }

    for (int cb = 0; cb < F; cb += 16) {
        // prop1: T1 = -d^2 (Aint @ Y[:, cb:cb+16])
        dense_prop<0>(A, aintg, arow0, arow1, has2, cb, T1OFF, cb + n16,
                      rb0, rb1, dv0, dv1, lane);
        __syncthreads();
        // prop2: T2 = -2 d^2 (Aint @ T1) - Y[:, cb:cb+16]
        dense_prop<1>(A, aintg, arow0, arow1, has2, T1OFF, T2OFF, cb + n16,
                      rb0, rb1, dv0, dv1, lane);
        __syncthreads();

        // W partial: chunk K-layout [Y16 | T1_16 | T2_16 | zero16], 2 K-steps
#pragma unroll
        for (int ks = 0; ks < 2; ks++) {
            int wr, aoff;
            if (ks == 0) {
                wr   = (q == 0) ? cb : (q == 1) ? cb + 8 : (q == 2) ? F + cb : F + cb + 8;
                aoff = (q == 0) ? cb : (q == 1) ? cb + 8 : (q == 2) ? T1OFF  : T1OFF + 8;
            } else {
                wr   = (q == 0) ? 2*F + cb : (q == 1) ? 2*F + cb + 8 : (q == 2) ? 3*F : 3*F + 8;
                aoff = (q == 0) ? T2OFF    : (q == 1) ? T2OFF + 8    : (q == 2) ? T1OFF : T1OFF + 8;
            }
            const short8 bhi = *(const short8*)&whi[ncol * RK + wr];
            const short8 blo = *(const short8*)&wlo[ncol * RK + wr];
#pragma unroll
            for (int t = 0; t < 7; t++) {
                const int row = ((t < 6) ? t * 16 : 84) + n16;
                const float* xp = &A[row * ASTR + aoff];
                const float4 v0 = *(const float4*)xp;
                const float4 v1 = *(const float4*)(xp + 4);
                short8 ahi, alo; short h, l;
                bsplit(v0.x, h, l); ahi[0] = h; alo[0] = l;
                bsplit(v0.y, h, l); ahi[1] = h; alo[1] = l;
                bsplit(v0.z, h, l); ahi[2] = h; alo[2] = l;
                bsplit(v0.w, h, l); ahi[3] = h; alo[3] = l;
                bsplit(v1.x, h, l); ahi[4] = h; alo[4] = l;
                bsplit(v1.y, h, l); ahi[5] = h; alo[5] = l;
                bsplit(v1.z, h, l); ahi[6] = h; alo[6] = l;
                bsplit(v1.w, h, l); ahi[7] = h; alo[7] = l;
                acc[t] = __builtin_amdgcn_mfma_f32_16x16x32_bf16(ahi, bhi, acc[t], 0, 0, 0);
                acc[t] = __builtin_amdgcn_mfma_f32_16x16x32_bf16(ahi, blo, acc[t], 0, 0, 0);
                acc[t] = __builtin_amdgcn_mfma_f32_16x16x32_bf16(alo, bhi, acc[t], 0, 0, 0);
            }
        }
        __syncthreads();
    }

    // Epilogue (D: col=lane&15, row=4*(lane>>4)+reg; tile 6 -> rows 84..99)
    const float bcol = bias[ncol];
#pragma unroll
    for (int t = 0; t < 7; t++) {
        const int rbase = ((t < 6) ? t * 16 : 84) + q * 4;
#pragma unroll
        for (int r = 0; r < 4; r++) {
            const int row = rbase + r;
            if (t < 6 || row >= 96) {
                const float dn = A[row * ASTR + DINVC];
                const float v = acc[t][r];
                float o;
                if (FINAL) o = fmaxf(v * (1.0f / dn) + bcol, 0.f);
                else       o = fmaxf(v + bcol * dn, 0.f);
                A[row * ASTR + ncol] = o;
            }
        }
    }
    __syncthreads();
}

__global__ __launch_bounds__(256, 4) void gnn_kernel(
    const float* __restrict__ feat,
    const int* __restrict__ src, const int* __restrict__ dst,
    const float* __restrict__ b1, const float* __restrict__ b2,
    const float* __restrict__ b3,
    const float* __restrict__ Wfc, const float* __restrict__ bfc,
    const short* __restrict__ wt, const short* __restrict__ aint,
    float* __restrict__ out)
{
    __shared__ __align__(16) float A[P * ASTR];   // 40,000 B
    const int g = blockIdx.x;
    const int tid = threadIdx.x;
    const int base = g * P;
    const int* dstg = dst + g * EPG;

    // ---- degree count (col DEGC) ----
    for (int i = tid; i < P; i += 256) *(int*)&A[i * ASTR + DEGC] = 0;
    __syncthreads();
    for (int e = tid; e < EPG; e += 256) {
        int d = dstg[e] - base;
        atomicAdd((int*)&A[d * ASTR + DEGC], 1);
    }
    __syncthreads();
    for (int i = tid; i < P; i += 256) {
        int dg = *(int*)&A[i * ASTR + DEGC];
        A[i * ASTR + DINVC] = rsqrtf((float)(dg > 1 ? dg : 1));
    }
    __syncthreads();

    // ---- feat load prescaled (Y = dinv*feat) ----
    for (int i = tid; i < P * INF / 4; i += 256) {
        int n = i >> 2, fq = (i & 3) * 4;
        float4 v = *(const float4*)&feat[(size_t)base * INF + i * 4];
        float dn = A[n * ASTR + DINVC];
        v.x *= dn; v.y *= dn; v.z *= dn; v.w *= dn;
        *(float4*)&A[n * ASTR + fq] = v;
    }
    __syncthreads();

    // ---- per-wave tile assignment + dinv preload for prop epilogues ----
    const int lane = tid & 63, wv = tid >> 6, q = lane >> 4;
    const int rb0 = wv * 16;
    const int t2i = wv + 4;
    const int rb1 = (t2i >= 6) ? 84 : t2i * 16;
    const bool has2 = (wv < 3);
    f32x4 dv0, dv1;
#pragma unroll
    for (int r = 0; r < 4; r++) {
        dv0[r] = A[(rb0 + q * 4 + r) * ASTR + DINVC];
        dv1[r] = A[((has2 ? rb1 : rb0) + q * 4 + r) * ASTR + DINVC];
    }

    const short* aintg = aint + (size_t)g * AINT_SZ;
    cheb_layer<INF, 0>(A, aintg, wt + L1HI, wt + L1LO, b1, tid, rb0, rb1, has2, dv0, dv1);
    cheb_layer<HID, 0>(A, aintg, wt + L2HI, wt + L2LO, b2, tid, rb0, rb1, has2, dv0, dv1);
    cheb_layer<HID, 1>(A, aintg, wt + L3HI, wt + L3LO, b3, tid, rb0, rb1, has2, dv0, dv1);

    // ---- mean pool + FC (psum in the now-free T1/T2 slots) ----
    {
        const int l2 = tid & 63, w = tid >> 6;
        float s = 0.f;
        for (int n = w; n < P; n += 4) s += A[n * ASTR + l2];
        A[l2 * ASTR + T1OFF + w] = s;
    }
    __syncthreads();
    if (tid < HID) {
        float hg = (A[tid * ASTR + T1OFF] + A[tid * ASTR + T1OFF + 1] +
                    A[tid * ASTR + T1OFF + 2] + A[tid * ASTR + T1OFF + 3]) * (1.0f / P);
        A[tid * ASTR + T1OFF + 4] = hg;
    }
    __syncthreads();
    if (tid < NOUT) {
        float o = bfc[tid];
        for (int c = 0; c < HID; c++) o += A[c * ASTR + T1OFF + 4] * Wfc[c * NOUT + tid];
        out[g * NOUT + tid] = o;
    }
}

extern "C" void kernel_launch(void* const* d_in, const int* in_sizes, int n_in,
                              void* d_out, int out_size, void* d_ws, size_t ws_size,
                              hipStream_t stream)
{
    const float* feat = (const float*)d_in[0];
    const int*   src  = (const int*)d_in[1];
    const int*   dst  = (const int*)d_in[2];
    const float* W1  = (const float*)d_in[5];
    const float* b1  = (const float*)d_in[6];
    const float* W2  = (const float*)d_in[7];
    const float* b2  = (const float*)d_in[8];
    const float* W3  = (const float*)d_in[9];
    const float* b3  = (const float*)d_in[10];
    const float* Wfc = (const float*)d_in[11];
    const float* bfc = (const float*)d_in[12];
    float* out = (float*)d_out;

    short* wt   = (short*)d_ws;                 // 122,880 B
    short* aint = wt + WT_SHORTS;               // + 25,600,000 B (ws >= 25.8 MB)

    wprep<<<64, 256, 0, stream>>>(W1, W2, W3, wt);
    abuild<<<NGRAPH, 256, 0, stream>>>(src, dst, aint);
    gnn_kernel<<<NGRAPH, 256, 0, stream>>>(feat, src, dst,
                                           b1, b2, b3, Wfc, bfc, wt, aint, out);
}